// Round 1
// baseline (77.941 us; speedup 1.0000x reference)
//
#include <hip/hip_runtime.h>

// ConvInsert: inputs (32,256,4096) f32, w1/w2 (16,1), b (1022,1).
// Per row: 511 overlapping windows of 16 (stride 8). Output per window:
// [slice_i(8 floats), dot(window,w1)+b[2i], dot(window,w2)+b[2i+1]],
// then the final 8-float slice. Row out length = 511*10 + 8 = 5118.

#define N_IN    4096
#define NW      511
#define ROW_OUT 5118
#define BLOCK   256

__global__ __launch_bounds__(BLOCK)
void ConvInsert_kernel(const float* __restrict__ in,
                       const float* __restrict__ w1,
                       const float* __restrict__ w2,
                       const float* __restrict__ b,
                       float* __restrict__ out)
{
    __shared__ float sw1[16];
    __shared__ float sw2[16];
    const int tid = threadIdx.x;
    if (tid < 16)       sw1[tid]      = w1[tid];
    else if (tid < 32)  sw2[tid - 16] = w2[tid - 16];
    __syncthreads();

    float rw1[16], rw2[16];
#pragma unroll
    for (int j = 0; j < 16; ++j) { rw1[j] = sw1[j]; rw2[j] = sw2[j]; }

    const int row = blockIdx.x;
    const float* __restrict__ inr  = in  + (size_t)row * N_IN;
    float*       __restrict__ outr = out + (size_t)row * ROW_OUT;

    for (int i = tid; i < NW; i += BLOCK) {
        const float* p = inr + 8 * i;           // 32B-aligned
        float4 a = *(const float4*)(p + 0);
        float4 c = *(const float4*)(p + 4);
        float4 d = *(const float4*)(p + 8);
        float4 e = *(const float4*)(p + 12);
        float x[16] = {a.x, a.y, a.z, a.w, c.x, c.y, c.z, c.w,
                       d.x, d.y, d.z, d.w, e.x, e.y, e.z, e.w};
        float d1 = 0.f, d2 = 0.f;
#pragma unroll
        for (int j = 0; j < 16; ++j) {
            d1 = fmaf(x[j], rw1[j], d1);
            d2 = fmaf(x[j], rw2[j], d2);
        }
        float2 bb = *(const float2*)(b + 2 * i);  // 8B-aligned
        float* o = outr + 10 * i;                  // 8B-aligned
        *(float2*)(o + 0) = make_float2(x[0], x[1]);
        *(float2*)(o + 2) = make_float2(x[2], x[3]);
        *(float2*)(o + 4) = make_float2(x[4], x[5]);
        *(float2*)(o + 6) = make_float2(x[6], x[7]);
        *(float2*)(o + 8) = make_float2(d1 + bb.x, d2 + bb.y);
    }

    // Tail: copy the final half-slice (8 floats).
    if (tid < 8) {
        outr[NW * 10 + tid] = inr[N_IN - 8 + tid];
    }
}

extern "C" void kernel_launch(void* const* d_in, const int* in_sizes, int n_in,
                              void* d_out, int out_size, void* d_ws, size_t ws_size,
                              hipStream_t stream) {
    const float* in = (const float*)d_in[0];
    const float* w1 = (const float*)d_in[1];
    const float* w2 = (const float*)d_in[2];
    const float* b  = (const float*)d_in[3];
    float* out = (float*)d_out;

    const int rows = 32 * 256;
    ConvInsert_kernel<<<rows, BLOCK, 0, stream>>>(in, w1, w2, b, out);
}

// Round 2
// 56.375 us; speedup vs baseline: 1.3825x; 1.3825x over previous
//
#include <hip/hip_runtime.h>

// ConvInsert: inputs (32,256,4096) f32, w1/w2 (16,1), b (1022,1).
// Per row: 511 overlapping windows of 16 (stride 8). Output per window:
// [slice_i(8 floats), dot(w1)+b[2i], dot(w2)+b[2i+1]], then final slice.
// Row out length = 511*10 + 8 = 5118 floats (20472 B -> only 8B-aligned
// per row, so the coalesced flush uses float2).
//
// R2: stage the output row in LDS (scatter there), flush contiguously.

#define N_IN    4096
#define NW      511
#define ROW_OUT 5118
#define BLOCK   256

__global__ __launch_bounds__(BLOCK)
void ConvInsert_kernel(const float* __restrict__ in,
                       const float* __restrict__ w1,
                       const float* __restrict__ w2,
                       const float* __restrict__ b,
                       float* __restrict__ out)
{
    __shared__ float so[ROW_OUT];          // 20472 B
    __shared__ float sw1[16];
    __shared__ float sw2[16];
    const int tid = threadIdx.x;
    if (tid < 16)       sw1[tid]      = w1[tid];
    else if (tid < 32)  sw2[tid - 16] = w2[tid - 16];
    __syncthreads();

    float rw1[16], rw2[16];
#pragma unroll
    for (int j = 0; j < 16; ++j) { rw1[j] = sw1[j]; rw2[j] = sw2[j]; }

    const int row = blockIdx.x;
    const float* __restrict__ inr  = in  + (size_t)row * N_IN;
    float*       __restrict__ outr = out + (size_t)row * ROW_OUT;

    for (int i = tid; i < NW; i += BLOCK) {
        const float* p = inr + 8 * i;            // 32B-aligned
        float4 a = *(const float4*)(p + 0);
        float4 c = *(const float4*)(p + 4);
        float4 d = *(const float4*)(p + 8);
        float4 e = *(const float4*)(p + 12);
        float x[16] = {a.x, a.y, a.z, a.w, c.x, c.y, c.z, c.w,
                       d.x, d.y, d.z, d.w, e.x, e.y, e.z, e.w};
        float d1 = 0.f, d2 = 0.f;
#pragma unroll
        for (int j = 0; j < 16; ++j) {
            d1 = fmaf(x[j], rw1[j], d1);
            d2 = fmaf(x[j], rw2[j], d2);
        }
        float2 bb = *(const float2*)(b + 2 * i);
        float* o = so + 10 * i;                  // LDS scatter, 2-way max
        *(float2*)(o + 0) = make_float2(x[0], x[1]);
        *(float2*)(o + 2) = make_float2(x[2], x[3]);
        *(float2*)(o + 4) = make_float2(x[4], x[5]);
        *(float2*)(o + 6) = make_float2(x[6], x[7]);
        *(float2*)(o + 8) = make_float2(d1 + bb.x, d2 + bb.y);
    }

    // Tail: final half-slice (8 floats) into LDS.
    if (tid < 8) {
        so[NW * 10 + tid] = inr[N_IN - 8 + tid];
    }
    __syncthreads();

    // Coalesced flush: 5118 floats = 2559 float2 (8B-aligned every row).
    const float2* __restrict__ s2 = (const float2*)so;
    float2*       __restrict__ o2 = (float2*)outr;
#pragma unroll 2
    for (int j = tid; j < ROW_OUT / 2; j += BLOCK) {
        o2[j] = s2[j];
    }
}

extern "C" void kernel_launch(void* const* d_in, const int* in_sizes, int n_in,
                              void* d_out, int out_size, void* d_ws, size_t ws_size,
                              hipStream_t stream) {
    const float* in = (const float*)d_in[0];
    const float* w1 = (const float*)d_in[1];
    const float* w2 = (const float*)d_in[2];
    const float* b  = (const float*)d_in[3];
    float* out = (float*)d_out;

    const int rows = 32 * 256;
    ConvInsert_kernel<<<rows, BLOCK, 0, stream>>>(in, w1, w2, b, out);
}

// Round 4
// 51.185 us; speedup vs baseline: 1.5227x; 1.1014x over previous
//
#include <hip/hip_runtime.h>

// ConvInsert: inputs (32,256,4096) f32, w1/w2 (16,1), b (1022,1).
// Per row: 511 overlapping windows of 16 (stride 8). Output per window:
// [slice_i(8 floats), dot(w1)+b[2i], dot(w2)+b[2i+1]], then final slice.
// Row out length = 5118 floats = 20472 B (8B-aligned only).
//
// R4: TWO rows per block -> pair output = 40944 B = 2559 float4, exactly
// 16B-aligned every pair. LDS-stage both rows, flush with ext-vector f32x4
// (global_store_dwordx4 nt) + ds_read_b128 (conflict-free).

#define N_IN     4096
#define NW       511
#define ROW_OUT  5118
#define BLOCK    512
#define PAIR_OUT (2 * ROW_OUT)            // 10236 floats = 2559 float4

typedef float f32x4 __attribute__((ext_vector_type(4)));

__global__ __launch_bounds__(BLOCK)
void ConvInsert_kernel(const float* __restrict__ in,
                       const float* __restrict__ w1,
                       const float* __restrict__ w2,
                       const float* __restrict__ b,
                       float* __restrict__ out)
{
    __shared__ float so[PAIR_OUT];        // 40944 B
    __shared__ float sw1[16];
    __shared__ float sw2[16];
    const int tid = threadIdx.x;
    if (tid < 16)       sw1[tid]      = w1[tid];
    else if (tid < 32)  sw2[tid - 16] = w2[tid - 16];
    __syncthreads();

    float rw1[16], rw2[16];
#pragma unroll
    for (int j = 0; j < 16; ++j) { rw1[j] = sw1[j]; rw2[j] = sw2[j]; }

    const int r    = tid >> 8;            // 0/1: which row this half-block does
    const int wt   = tid & 255;
    const int row  = 2 * blockIdx.x + r;
    const float* __restrict__ inr = in + (size_t)row * N_IN;
    float* __restrict__ sor = so + r * ROW_OUT;

    for (int i = wt; i < NW; i += 256) {
        const float* p = inr + 8 * i;     // 32B-aligned
        float4 a = *(const float4*)(p + 0);
        float4 c = *(const float4*)(p + 4);
        float4 d = *(const float4*)(p + 8);
        float4 e = *(const float4*)(p + 12);
        float x[16] = {a.x, a.y, a.z, a.w, c.x, c.y, c.z, c.w,
                       d.x, d.y, d.z, d.w, e.x, e.y, e.z, e.w};
        float d1 = 0.f, d2 = 0.f;
#pragma unroll
        for (int j = 0; j < 16; ++j) {
            d1 = fmaf(x[j], rw1[j], d1);
            d2 = fmaf(x[j], rw2[j], d2);
        }
        float2 bb = *(const float2*)(b + 2 * i);
        float* o = sor + 10 * i;          // LDS scatter
        *(float2*)(o + 0) = make_float2(x[0], x[1]);
        *(float2*)(o + 2) = make_float2(x[2], x[3]);
        *(float2*)(o + 4) = make_float2(x[4], x[5]);
        *(float2*)(o + 6) = make_float2(x[6], x[7]);
        *(float2*)(o + 8) = make_float2(d1 + bb.x, d2 + bb.y);
    }

    // Tail: final half-slice (8 floats) of each row.
    if (wt < 8) {
        sor[NW * 10 + wt] = inr[N_IN - 8 + wt];
    }
    __syncthreads();

    // Coalesced flush: 2559 float4, pair base 16B-aligned.
    const f32x4* __restrict__ s4 = (const f32x4*)so;
    f32x4* __restrict__ o4 =
        (f32x4*)(out + (size_t)blockIdx.x * PAIR_OUT);
#pragma unroll 5
    for (int j = tid; j < PAIR_OUT / 4; j += BLOCK) {
        __builtin_nontemporal_store(s4[j], o4 + j);
    }
}

extern "C" void kernel_launch(void* const* d_in, const int* in_sizes, int n_in,
                              void* d_out, int out_size, void* d_ws, size_t ws_size,
                              hipStream_t stream) {
    const float* in = (const float*)d_in[0];
    const float* w1 = (const float*)d_in[1];
    const float* w2 = (const float*)d_in[2];
    const float* b  = (const float*)d_in[3];
    float* out = (float*)d_out;

    const int pairs = (32 * 256) / 2;     // 4096 blocks, 2 rows each
    ConvInsert_kernel<<<pairs, BLOCK, 0, stream>>>(in, w1, w2, b, out);
}

// Round 5
// 50.793 us; speedup vs baseline: 1.5345x; 1.0077x over previous
//
#include <hip/hip_runtime.h>

// ConvInsert: inputs (32,256,4096) f32, w1/w2 (16,1), b (1022,1).
// Per row: 511 overlapping windows of 16 (stride 8). Output per window:
// [slice_i(8 floats), dot(w1)+b[2i], dot(w2)+b[2i+1]], then final slice.
// Row out = 5118 floats = 20472 B -> row base byte = 8*(row&1) mod 16.
//
// R5: ONE row per 256-thread block, 20.5 KB LDS -> 7 blocks/CU (28 waves,
// was 24). Odd-row misalignment handled at flush: 2-float head, then 1279
// aligned float4 nt stores. Weights loaded with uniform indices -> SGPRs
// (no LDS staging for weights, one barrier total).

#define N_IN    4096
#define NW      511
#define ROW_OUT 5118
#define BLOCK   256
#define NF4     1279              // float4 count in the aligned flush body

typedef float f32x4 __attribute__((ext_vector_type(4)));

__global__ __launch_bounds__(BLOCK)
void ConvInsert_kernel(const float* __restrict__ in,
                       const float* __restrict__ w1,
                       const float* __restrict__ w2,
                       const float* __restrict__ b,
                       float* __restrict__ out)
{
    __shared__ __align__(16) float so[ROW_OUT];   // 20472 B
    const int tid = threadIdx.x;

    // Wave-uniform weight loads -> s_load into SGPRs.
    float rw1[16], rw2[16];
#pragma unroll
    for (int j = 0; j < 16; ++j) { rw1[j] = w1[j]; rw2[j] = w2[j]; }

    const int row = blockIdx.x;
    const float* __restrict__ inr  = in  + (size_t)row * N_IN;
    float*       __restrict__ outr = out + (size_t)row * ROW_OUT;

    for (int i = tid; i < NW; i += BLOCK) {
        const float* p = inr + 8 * i;             // 32B-aligned
        float4 a = *(const float4*)(p + 0);
        float4 c = *(const float4*)(p + 4);
        float4 d = *(const float4*)(p + 8);
        float4 e = *(const float4*)(p + 12);
        float x[16] = {a.x, a.y, a.z, a.w, c.x, c.y, c.z, c.w,
                       d.x, d.y, d.z, d.w, e.x, e.y, e.z, e.w};
        float d1 = 0.f, d2 = 0.f;
#pragma unroll
        for (int j = 0; j < 16; ++j) {
            d1 = fmaf(x[j], rw1[j], d1);
            d2 = fmaf(x[j], rw2[j], d2);
        }
        float2 bb = *(const float2*)(b + 2 * i);
        float* o = so + 10 * i;                   // LDS scatter
        *(float2*)(o + 0) = make_float2(x[0], x[1]);
        *(float2*)(o + 2) = make_float2(x[2], x[3]);
        *(float2*)(o + 4) = make_float2(x[4], x[5]);
        *(float2*)(o + 6) = make_float2(x[6], x[7]);
        *(float2*)(o + 8) = make_float2(d1 + bb.x, d2 + bb.y);
    }

    // Tail: final half-slice (8 floats).
    if (tid < 8) {
        so[NW * 10 + tid] = inr[N_IN - 8 + tid];
    }
    __syncthreads();

    if ((row & 1) == 0) {
        // Row base 16B-aligned: direct float4 flush + float2 tail.
        const f32x4* __restrict__ s4 = (const f32x4*)so;
        f32x4* __restrict__ o4 = (f32x4*)outr;
#pragma unroll 5
        for (int j = tid; j < NF4; j += BLOCK) {
            __builtin_nontemporal_store(s4[j], o4 + j);
        }
        if (tid == 0) {
            *(float2*)(outr + ROW_OUT - 2) =
                make_float2(so[ROW_OUT - 2], so[ROW_OUT - 1]);
        }
    } else {
        // Row base == 8 mod 16: 2-float head, then aligned float4 body.
        if (tid == 0) {
            *(float2*)outr = make_float2(so[0], so[1]);
        }
        const float2* __restrict__ s2 = (const float2*)(so + 2); // 8B-aligned
        f32x4* __restrict__ o4 = (f32x4*)(outr + 2);             // 16B-aligned
#pragma unroll 5
        for (int j = tid; j < NF4; j += BLOCK) {
            float2 lo = s2[2 * j];
            float2 hi = s2[2 * j + 1];
            f32x4 v = {lo.x, lo.y, hi.x, hi.y};
            __builtin_nontemporal_store(v, o4 + j);
        }
    }
}

extern "C" void kernel_launch(void* const* d_in, const int* in_sizes, int n_in,
                              void* d_out, int out_size, void* d_ws, size_t ws_size,
                              hipStream_t stream) {
    const float* in = (const float*)d_in[0];
    const float* w1 = (const float*)d_in[1];
    const float* w2 = (const float*)d_in[2];
    const float* b  = (const float*)d_in[3];
    float* out = (float*)d_out;

    const int rows = 32 * 256;
    ConvInsert_kernel<<<rows, BLOCK, 0, stream>>>(in, w1, w2, b, out);
}